// Round 11
// baseline (335.963 us; speedup 1.0000x reference)
//
#include <hip/hip_runtime.h>
#include <hip/hip_bf16.h>
#include <stdint.h>

// Problem constants (FC_Caps): B=32, I=1024, O=64, D_out=32, D_in=16
#define B_  32
#define I_  1024
#define O_  64
#define D_  32
#define N_  16
#define OD_ 2048   // O_*D_

// ---------- bf16 helpers (bit-exact RNE pack, shift unpack) ----------
__device__ __forceinline__ uint32_t f2bf1(float f) {
  uint32_t u = __float_as_uint(f);
  return (u + 0x7fffu + ((u >> 16) & 1u)) >> 16;
}
__device__ __forceinline__ uint32_t pack2(float a, float b) {
  return f2bf1(a) | (f2bf1(b) << 16);
}
__device__ __forceinline__ float bflo(uint32_t v) { return __uint_as_float(v << 16); }
__device__ __forceinline__ float bfhi(uint32_t v) { return __uint_as_float(v & 0xffff0000u); }
__device__ __forceinline__ void unpack8(uint4 r, float* u) {
  u[0] = bflo(r.x); u[1] = bfhi(r.x);
  u[2] = bflo(r.y); u[3] = bfhi(r.y);
  u[4] = bflo(r.z); u[5] = bfhi(r.z);
  u[6] = bflo(r.w); u[7] = bfhi(r.w);
}

// ---------- K1: u_hat[b][i][od] = sum_n W[i,od,n] * x[b,i,n]  (bf16 out) ----------
// (frozen at R10 form, ~83 us: adjacent-od pair per thread, packed uint32 store,
// bit-exact u_hat. Three single-variable probes (R3/R7/R10) say this structure
// is at its local floor — LDS-broadcast issue ~41 us/CU + overlap losses.)
__global__ __launch_bounds__(256) void k_einsum(const float* __restrict__ x,
                                                const float* __restrict__ W,
                                                uint16_t* __restrict__ uhat) {
  const int i = blockIdx.x >> 2;
  const int q = blockIdx.x & 3;
  const int t = threadIdx.x;
  const int od0 = q * 512 + t * 2;      // this thread owns od0 and od0+1
  __shared__ float xs[B_ * N_];
  for (int e = t; e < B_ * N_; e += 256) {
    int bb = e >> 4, n = e & 15;
    xs[e] = x[(size_t)bb * (I_ * N_) + (size_t)i * N_ + n];
  }
  float wA[16], wB[16];
  {
    const float4* Wp = (const float4*)(W + (size_t)i * (OD_ * N_) + (size_t)od0 * N_);
    #pragma unroll
    for (int qq = 0; qq < 4; ++qq) {
      float4 fa = Wp[qq];
      wA[qq * 4 + 0] = fa.x; wA[qq * 4 + 1] = fa.y;
      wA[qq * 4 + 2] = fa.z; wA[qq * 4 + 3] = fa.w;
      float4 fb = Wp[4 + qq];
      wB[qq * 4 + 0] = fb.x; wB[qq * 4 + 1] = fb.y;
      wB[qq * 4 + 2] = fb.z; wB[qq * 4 + 3] = fb.w;
    }
  }
  __syncthreads();
  uint32_t* u32 = (uint32_t*)uhat;
  #pragma unroll 2
  for (int bb = 0; bb < B_; ++bb) {
    float4 x0 = ((const float4*)(xs + bb * 16))[0];
    float4 x1 = ((const float4*)(xs + bb * 16))[1];
    float4 x2 = ((const float4*)(xs + bb * 16))[2];
    float4 x3 = ((const float4*)(xs + bb * 16))[3];
    float xv[16] = {x0.x, x0.y, x0.z, x0.w, x1.x, x1.y, x1.z, x1.w,
                    x2.x, x2.y, x2.z, x2.w, x3.x, x3.y, x3.z, x3.w};
    float a0 = 0.f, a1 = 0.f;
    #pragma unroll
    for (int n = 0; n < 16; ++n) {
      a0 = fmaf(wA[n], xv[n], a0);
      a1 = fmaf(wB[n], xv[n], a1);
    }
    u32[(((size_t)bb * I_ + i) * OD_ + od0) >> 1] = pack2(a0, a1);
  }
}

// ---------- K2: iter-0 weighted sum (c exactly uniform). chunk=32 i, bf16 partials ----------
// (frozen — 25 us, proves the streaming pattern k_wsum inherits)
__global__ __launch_bounds__(256) void k_sum0(const uint4* __restrict__ uhat,
                                              uint4* __restrict__ part) {
  const int b = blockIdx.x >> 5, chunk = blockIdx.x & 31;
  const int t = threadIdx.x;
  float acc[8] = {0.f, 0.f, 0.f, 0.f, 0.f, 0.f, 0.f, 0.f};
  const size_t ubase = (((size_t)b * I_ + (size_t)chunk * 32) * OD_ + (size_t)t * 8) >> 3;
  #pragma unroll 8
  for (int ii = 0; ii < 32; ++ii) {
    uint4 r = uhat[ubase + (size_t)ii * (OD_ / 8)];
    float u[8]; unpack8(r, u);
    #pragma unroll
    for (int j = 0; j < 8; ++j) acc[j] += u[j];
  }
  part[(((size_t)b * 32 + chunk) * OD_ + (size_t)t * 8) >> 3] =
      make_uint4(pack2(acc[0], acc[1]), pack2(acc[2], acc[3]),
                 pack2(acc[4], acc[5]), pack2(acc[6], acc[7]));
}

// ---------- R11 NEW: k_agree — agreement dot + wave softmax, writes c fp32 ----------
// Route split part A. No s_acc (VGPR ~55 vs route's ~100+ -> occupancy cap
// lifted), no carried dependency across i (deep pipelining possible), grid
// 2048 (8 blocks/CU). bij ELIMINATED algebraically: softmax input at iter2
// is u.(v0+v1), and squash folds v0+v1 in place, so both agree passes are
// the same kernel reading the current v buffer. Dot/softmax code identical
// to the proven route (same fmaf order -> same rounding).
__global__ __launch_bounds__(256) void k_agree(const uint4* __restrict__ uhat,
                                               const float* __restrict__ v,
                                               float* __restrict__ cij) {
  const int b = blockIdx.x >> 6, chunk = blockIdx.x & 63;  // 64 chunks of 16 i
  const int t = threadIdx.x;
  const int w = t >> 6, lane = t & 63;   // lane = o
  uint32_t vp[16];
  {
    const float4* vpt = (const float4*)(v + ((size_t)b * 64 + lane) * 32);
    #pragma unroll
    for (int q = 0; q < 8; ++q) {
      float4 f = vpt[q];
      vp[2 * q]     = pack2(f.x, f.y);
      vp[2 * q + 1] = pack2(f.z, f.w);
    }
  }
  const int i0 = chunk * 16 + w * 4;     // 4 i per wave
  const uint4* ub = uhat + ((size_t)b * I_ + i0) * 256 + (size_t)lane * 4;
  for (int r = 0; r < 4; ++r) {
    const uint4* uc = ub + (size_t)r * 256;
    uint4 c0 = uc[0], c1 = uc[1], c2 = uc[2], c3 = uc[3];
    float a = 0.f;
    {
      float u8[8];
      unpack8(c0, u8);
      #pragma unroll
      for (int p = 0; p < 4; ++p) {
        uint32_t vv = vp[p];
        a = fmaf(u8[2 * p], bflo(vv), a);
        a = fmaf(u8[2 * p + 1], bfhi(vv), a);
      }
      unpack8(c1, u8);
      #pragma unroll
      for (int p = 0; p < 4; ++p) {
        uint32_t vv = vp[4 + p];
        a = fmaf(u8[2 * p], bflo(vv), a);
        a = fmaf(u8[2 * p + 1], bfhi(vv), a);
      }
      unpack8(c2, u8);
      #pragma unroll
      for (int p = 0; p < 4; ++p) {
        uint32_t vv = vp[8 + p];
        a = fmaf(u8[2 * p], bflo(vv), a);
        a = fmaf(u8[2 * p + 1], bfhi(vv), a);
      }
      unpack8(c3, u8);
      #pragma unroll
      for (int p = 0; p < 4; ++p) {
        uint32_t vv = vp[12 + p];
        a = fmaf(u8[2 * p], bflo(vv), a);
        a = fmaf(u8[2 * p + 1], bfhi(vv), a);
      }
    }
    // wave softmax over the 64 o's
    float m = a;
    #pragma unroll
    for (int off = 1; off <= 32; off <<= 1) m = fmaxf(m, __shfl_xor(m, off));
    float e = __expf(a - m);
    float sm = e;
    #pragma unroll
    for (int off = 1; off <= 32; off <<= 1) sm += __shfl_xor(sm, off);
    cij[((size_t)b * I_ + i0 + r) * 64 + lane] = e / sm;
  }
}

// ---------- R11 NEW: k_wsum — weighted sum with staged c (k_sum0 pattern) ----------
// Route split part B. Identical streaming structure to the 25-us k_sum0;
// c chunk (32 i x 64 o fp32 = 8 KB) staged in LDS, read as wave-broadcast
// (4 lanes share each o -> conflict-free). Same fp32 serial-32 sum tree as
// k_sum0 -> same precision class.
__global__ __launch_bounds__(256) void k_wsum(const uint4* __restrict__ uhat,
                                              const float* __restrict__ cij,
                                              uint4* __restrict__ part) {
  const int b = blockIdx.x >> 5, chunk = blockIdx.x & 31;
  const int t = threadIdx.x;
  __shared__ float cs[32 * 64];          // 8 KB
  {
    const float4* src = (const float4*)(cij + ((size_t)b * I_ + (size_t)chunk * 32) * 64);
    float4* dst = (float4*)cs;
    dst[t]       = src[t];
    dst[t + 256] = src[t + 256];
  }
  __syncthreads();
  const int o = t >> 2;                  // thread owns od = t*8 .. +7, all in this o
  float acc[8] = {0.f, 0.f, 0.f, 0.f, 0.f, 0.f, 0.f, 0.f};
  const size_t ubase = (((size_t)b * I_ + (size_t)chunk * 32) * OD_ + (size_t)t * 8) >> 3;
  #pragma unroll 8
  for (int ii = 0; ii < 32; ++ii) {
    uint4 r = uhat[ubase + (size_t)ii * (OD_ / 8)];
    const float c = cs[ii * 64 + o];
    float u[8]; unpack8(r, u);
    #pragma unroll
    for (int j = 0; j < 8; ++j) acc[j] = fmaf(c, u[j], acc[j]);
  }
  part[(((size_t)b * 32 + chunk) * OD_ + (size_t)t * 8) >> 3] =
      make_uint4(pack2(acc[0], acc[1]), pack2(acc[2], acc[3]),
                 pack2(acc[4], acc[5]), pack2(acc[6], acc[7]));
}

// ---------- squash: reduce 32 bf16 chunk-partials, scale, (+bias), squash over d ----------
// addPrev folds v_new += v_prev IN PLACE (enables the bij-free algebra:
// softmax input at iter2 = u.(v0+v1)). Per-element read-then-write by the
// same thread -> race-free.
__global__ __launch_bounds__(256) void k_squash(const uint16_t* __restrict__ part,
                                                const float* __restrict__ bias,
                                                float* __restrict__ vout,
                                                float scale, int addBias, int addPrev) {
  const int lane = threadIdx.x & 63;
  const int row = blockIdx.x * 4 + (threadIdx.x >> 6);  // b=row>>6, o=row&63
  const int b = row >> 6, o = row & 63;
  const int d = lane & 31;
  const uint16_t* p = part + (size_t)b * (32 * OD_) + (size_t)o * 32 + d;
  float s = 0.f;
  const int c0 = (lane >> 5) * 16;   // half-waves split the 32 chunks
  for (int c = c0; c < c0 + 16; ++c)
    s += __uint_as_float(((uint32_t)p[(size_t)c * OD_]) << 16);
  s += __shfl_xor(s, 32);
  s *= scale;
  if (addBias) s += bias[o * 32 + d];
  float dot = s * s;
  #pragma unroll
  for (int off = 1; off <= 16; off <<= 1) dot += __shfl_xor(dot, off);
  float sc = dot / (1.f + dot) / sqrtf(dot + 1e-8f);
  if (lane < 32) {
    float val = s * sc;
    if (addPrev) val += vout[(size_t)row * 32 + d];
    vout[(size_t)row * 32 + d] = val;
  }
}

extern "C" void kernel_launch(void* const* d_in, const int* in_sizes, int n_in,
                              void* d_out, int out_size, void* d_ws, size_t ws_size,
                              hipStream_t stream) {
  const float* x    = (const float*)d_in[0];  // [32,1024,16]
  const float* W    = (const float*)d_in[1];  // [1,1024,64,32,16]
  const float* bias = (const float*)d_in[2];  // [1,1,64,32]
  float* out = (float*)d_out;                 // [32,64,32]

  char* ws = (char*)d_ws;
  // Workspace layout (140.25 MiB — unchanged proven footprint):
  //   [0,128M)      uhat  bf16 u_hat[b][i][od]
  //   [128,136M)    cij   fp32 c[b,i,o]      (replaces bij — bij eliminated)
  //   [136,140M)    part  bf16 partials [b,32,od]
  //   [140M,+256K)  vbuf  fp32 v[b,od]  (v0, then v0+v1 in place)
  uint16_t* uhat1 = (uint16_t*)ws;
  uint4*    uhat4 = (uint4*)ws;
  float* cij  = (float*)(ws + 134217728ull);
  uint4* part = (uint4*)(ws + 134217728ull + 8388608ull);
  uint16_t* part16 = (uint16_t*)part;
  float* vbuf = (float*)(ws + 134217728ull + 8388608ull + 4194304ull);

  k_einsum<<<dim3(I_ * 4), dim3(256), 0, stream>>>(x, W, uhat1);
  // iter 0: uniform c = 1/64
  k_sum0  <<<dim3(1024), dim3(256), 0, stream>>>(uhat4, part);
  k_squash<<<dim3(512),  dim3(256), 0, stream>>>(part16, bias, vbuf, 1.f / 64.f, 0, 0);  // v = v0
  // iter 1: c1 = softmax(u.v0)
  k_agree <<<dim3(2048), dim3(256), 0, stream>>>(uhat4, vbuf, cij);
  k_wsum  <<<dim3(1024), dim3(256), 0, stream>>>(uhat4, cij, part);
  k_squash<<<dim3(512),  dim3(256), 0, stream>>>(part16, bias, vbuf, 1.f, 0, 1);         // v = v0+v1
  // iter 2 (last): c2 = softmax(u.(v0+v1)); + bias on output
  k_agree <<<dim3(2048), dim3(256), 0, stream>>>(uhat4, vbuf, cij);
  k_wsum  <<<dim3(1024), dim3(256), 0, stream>>>(uhat4, cij, part);
  k_squash<<<dim3(512),  dim3(256), 0, stream>>>(part16, bias, out, 1.f, 1, 0);
}

// Round 12
// 295.615 us; speedup vs baseline: 1.1365x; 1.1365x over previous
//
#include <hip/hip_runtime.h>
#include <hip/hip_bf16.h>
#include <stdint.h>

// Problem constants (FC_Caps): B=32, I=1024, O=64, D_out=32, D_in=16
#define B_  32
#define I_  1024
#define O_  64
#define D_  32
#define N_  16
#define OD_ 2048   // O_*D_

// u_hat PERMUTED layout (R12): per (b,i) row of 4 KB, element (o,d) lives at
// bf16 offset  (d>>3)*512 + o*8 + (d&7).  [k-block][o][j]
// -> route lane=o reads 4 fully-dense 1-KB wave segments (was 64-B lane
//    stride = 4x L1 transactions; the measured 25us-vs-80us separator
//    between k_sum0 and k_route on the same 128 MB stream).

// ---------- bf16 helpers (bit-exact RNE pack, shift unpack) ----------
__device__ __forceinline__ uint32_t f2bf1(float f) {
  uint32_t u = __float_as_uint(f);
  return (u + 0x7fffu + ((u >> 16) & 1u)) >> 16;
}
__device__ __forceinline__ uint32_t pack2(float a, float b) {
  return f2bf1(a) | (f2bf1(b) << 16);
}
__device__ __forceinline__ float bflo(uint32_t v) { return __uint_as_float(v << 16); }
__device__ __forceinline__ float bfhi(uint32_t v) { return __uint_as_float(v & 0xffff0000u); }
__device__ __forceinline__ void unpack8(uint4 r, float* u) {
  u[0] = bflo(r.x); u[1] = bfhi(r.x);
  u[2] = bflo(r.y); u[3] = bfhi(r.y);
  u[4] = bflo(r.z); u[5] = bfhi(r.z);
  u[6] = bflo(r.w); u[7] = bfhi(r.w);
}

// ---------- K1: einsum, R10 compute (bit-exact), permuted store ----------
// Thread owns uint32 unit u = q*256 + t of the (b,i) row: k=q, o=(u>>2)&63,
// dp=u&3 -> od0 = o*32 + k*8 + dp*2 (and od0+1). W rows od0,od0+1 are 128 B
// contiguous (same as R10); stores stay one dense uint32 per (b,i).
__global__ __launch_bounds__(256) void k_einsum(const float* __restrict__ x,
                                                const float* __restrict__ W,
                                                uint16_t* __restrict__ uhat) {
  const int i = blockIdx.x >> 2;
  const int q = blockIdx.x & 3;
  const int t = threadIdx.x;
  const int u = q * 256 + t;            // uint32 unit within the 1024-unit row
  const int o  = (u >> 2) & 63;
  const int dp = u & 3;
  const int od0 = o * 32 + q * 8 + dp * 2;   // this thread owns od0, od0+1
  __shared__ float xs[B_ * N_];
  for (int e = t; e < B_ * N_; e += 256) {
    int bb = e >> 4, n = e & 15;
    xs[e] = x[(size_t)bb * (I_ * N_) + (size_t)i * N_ + n];
  }
  float wA[16], wB[16];
  {
    const float4* Wp = (const float4*)(W + (size_t)i * (OD_ * N_) + (size_t)od0 * N_);
    #pragma unroll
    for (int qq = 0; qq < 4; ++qq) {
      float4 fa = Wp[qq];
      wA[qq * 4 + 0] = fa.x; wA[qq * 4 + 1] = fa.y;
      wA[qq * 4 + 2] = fa.z; wA[qq * 4 + 3] = fa.w;
      float4 fb = Wp[4 + qq];
      wB[qq * 4 + 0] = fb.x; wB[qq * 4 + 1] = fb.y;
      wB[qq * 4 + 2] = fb.z; wB[qq * 4 + 3] = fb.w;
    }
  }
  __syncthreads();
  uint32_t* u32 = (uint32_t*)uhat;
  #pragma unroll 2
  for (int bb = 0; bb < B_; ++bb) {
    float4 x0 = ((const float4*)(xs + bb * 16))[0];
    float4 x1 = ((const float4*)(xs + bb * 16))[1];
    float4 x2 = ((const float4*)(xs + bb * 16))[2];
    float4 x3 = ((const float4*)(xs + bb * 16))[3];
    float xv[16] = {x0.x, x0.y, x0.z, x0.w, x1.x, x1.y, x1.z, x1.w,
                    x2.x, x2.y, x2.z, x2.w, x3.x, x3.y, x3.z, x3.w};
    float a0 = 0.f, a1 = 0.f;
    #pragma unroll
    for (int n = 0; n < 16; ++n) {
      a0 = fmaf(wA[n], xv[n], a0);
      a1 = fmaf(wB[n], xv[n], a1);
    }
    u32[((size_t)bb * I_ + i) * 1024 + u] = pack2(a0, a1);
  }
}

// ---------- K2: iter-0 sum — element-wise over the stream, layout-agnostic ----------
// (frozen 25-us pattern; part output inherits the permuted layout)
__global__ __launch_bounds__(256) void k_sum0(const uint4* __restrict__ uhat,
                                              uint4* __restrict__ part) {
  const int b = blockIdx.x >> 5, chunk = blockIdx.x & 31;
  const int t = threadIdx.x;
  float acc[8] = {0.f, 0.f, 0.f, 0.f, 0.f, 0.f, 0.f, 0.f};
  const size_t ubase = (((size_t)b * I_ + (size_t)chunk * 32) * OD_ + (size_t)t * 8) >> 3;
  #pragma unroll 8
  for (int ii = 0; ii < 32; ++ii) {
    uint4 r = uhat[ubase + (size_t)ii * (OD_ / 8)];
    float u[8]; unpack8(r, u);
    #pragma unroll
    for (int j = 0; j < 8; ++j) acc[j] += u[j];
  }
  part[(((size_t)b * 32 + chunk) * OD_ + (size_t)t * 8) >> 3] =
      make_uint4(pack2(acc[0], acc[1]), pack2(acc[2], acc[3]),
                 pack2(acc[4], acc[5]), pack2(acc[6], acc[7]));
}

// ---------- squash: permuted part indexing; addPrev folds v += v_prev (bij-free algebra) ----------
__global__ __launch_bounds__(256) void k_squash(const uint16_t* __restrict__ part,
                                                const float* __restrict__ bias,
                                                float* __restrict__ vout,
                                                float scale, int addBias, int addPrev) {
  const int lane = threadIdx.x & 63;
  const int row = blockIdx.x * 4 + (threadIdx.x >> 6);  // b=row>>6, o=row&63
  const int b = row >> 6, o = row & 63;
  const int d = lane & 31;
  // permuted: element (o,d) at (d>>3)*512 + o*8 + (d&7) within each 2048 row
  const uint16_t* p = part + (size_t)b * (32 * OD_) +
                      (size_t)(d >> 3) * 512 + (size_t)o * 8 + (d & 7);
  float s = 0.f;
  const int c0 = (lane >> 5) * 16;   // half-waves split the 32 chunks
  for (int c = c0; c < c0 + 16; ++c)
    s += __uint_as_float(((uint32_t)p[(size_t)c * OD_]) << 16);
  s += __shfl_xor(s, 32);
  s *= scale;
  if (addBias) s += bias[o * 32 + d];
  float dot = s * s;
  #pragma unroll
  for (int off = 1; off <= 16; off <<= 1) dot += __shfl_xor(dot, off);
  float sc = dot / (1.f + dot) / sqrtf(dot + 1e-8f);
  if (lane < 32) {
    float val = s * sc;
    if (addPrev) val += vout[(size_t)row * 32 + d];
    vout[(size_t)row * 32 + d] = val;
  }
}

// ---------- route (iters 1,2): monolithic (R11 proved 1 pass > 2), DENSE loads ----------
// bij-free: softmax input at iter2 = u.(v0+v1), with v-fold done in squash
// (verified PASSED in R11). Loads: lane o reads uint4 at k*64+o -> four 1-KB
// dense wave segments per i. Dot/softmax/accum FMA order identical to the
// proven route -> numerics unchanged. Final part store dense (uint4 at t).
__global__ __launch_bounds__(256) void k_route(const uint4* __restrict__ uhat,
                                               const float* __restrict__ vprev,
                                               uint4* __restrict__ part) {
  const int b = blockIdx.x >> 5, chunk = blockIdx.x & 31;
  const int t = threadIdx.x;
  const int w = t >> 6, lane = t & 63;   // lane = o
  __shared__ float red[4][64][32];       // 32 KB, swizzled [w][o][(d+o)&31]
  uint32_t vp[16];
  {
    const float4* vpt = (const float4*)(vprev + ((size_t)b * 64 + lane) * 32);
    #pragma unroll
    for (int q = 0; q < 8; ++q) {
      float4 f = vpt[q];
      vp[2 * q]     = pack2(f.x, f.y);
      vp[2 * q + 1] = pack2(f.z, f.w);
    }
  }
  float s_acc[32];
  #pragma unroll
  for (int d = 0; d < 32; ++d) s_acc[d] = 0.f;
  const int i0 = chunk * 32 + w * 8;
  const uint4* ub = uhat + ((size_t)b * I_ + i0) * 256 + lane;  // dense: +k*64 per frag
  for (int r = 0; r < 8; ++r) {
    const uint4* uc = ub + (size_t)r * 256;
    uint4 c0 = uc[0], c1 = uc[64], c2 = uc[128], c3 = uc[192];
    float a = 0.f;
    {
      float u8[8];
      unpack8(c0, u8);
      #pragma unroll
      for (int p = 0; p < 4; ++p) {
        uint32_t vv = vp[p];
        a = fmaf(u8[2 * p], bflo(vv), a);
        a = fmaf(u8[2 * p + 1], bfhi(vv), a);
      }
      unpack8(c1, u8);
      #pragma unroll
      for (int p = 0; p < 4; ++p) {
        uint32_t vv = vp[4 + p];
        a = fmaf(u8[2 * p], bflo(vv), a);
        a = fmaf(u8[2 * p + 1], bfhi(vv), a);
      }
      unpack8(c2, u8);
      #pragma unroll
      for (int p = 0; p < 4; ++p) {
        uint32_t vv = vp[8 + p];
        a = fmaf(u8[2 * p], bflo(vv), a);
        a = fmaf(u8[2 * p + 1], bfhi(vv), a);
      }
      unpack8(c3, u8);
      #pragma unroll
      for (int p = 0; p < 4; ++p) {
        uint32_t vv = vp[12 + p];
        a = fmaf(u8[2 * p], bflo(vv), a);
        a = fmaf(u8[2 * p + 1], bfhi(vv), a);
      }
    }
    // wave softmax over the 64 o's
    float m = a;
    #pragma unroll
    for (int off = 1; off <= 32; off <<= 1) m = fmaxf(m, __shfl_xor(m, off));
    float e = __expf(a - m);
    float sm = e;
    #pragma unroll
    for (int off = 1; off <= 32; off <<= 1) sm += __shfl_xor(sm, off);
    const float c = e / sm;
    {
      float u8[8];
      unpack8(c0, u8);
      #pragma unroll
      for (int j = 0; j < 8; ++j) s_acc[j] = fmaf(c, u8[j], s_acc[j]);
      unpack8(c1, u8);
      #pragma unroll
      for (int j = 0; j < 8; ++j) s_acc[8 + j] = fmaf(c, u8[j], s_acc[8 + j]);
      unpack8(c2, u8);
      #pragma unroll
      for (int j = 0; j < 8; ++j) s_acc[16 + j] = fmaf(c, u8[j], s_acc[16 + j]);
      unpack8(c3, u8);
      #pragma unroll
      for (int j = 0; j < 8; ++j) s_acc[24 + j] = fmaf(c, u8[j], s_acc[24 + j]);
    }
  }
  // combine 4 waves' [o][d] partials (swizzle: 2 lanes/bank = free)
  #pragma unroll
  for (int d = 0; d < 32; ++d) red[w][lane][(d + lane) & 31] = s_acc[d];
  __syncthreads();
  {
    const int o = t & 63, k = t >> 6;    // thread stores uint4 at dense index t
    float sum[8];
    #pragma unroll
    for (int j = 0; j < 8; ++j) {
      const int sw = (k * 8 + j + o) & 31;
      sum[j] = red[0][o][sw] + red[1][o][sw] + red[2][o][sw] + red[3][o][sw];
    }
    part[((size_t)b * 32 + chunk) * 256 + t] =
        make_uint4(pack2(sum[0], sum[1]), pack2(sum[2], sum[3]),
                   pack2(sum[4], sum[5]), pack2(sum[6], sum[7]));
  }
}

extern "C" void kernel_launch(void* const* d_in, const int* in_sizes, int n_in,
                              void* d_out, int out_size, void* d_ws, size_t ws_size,
                              hipStream_t stream) {
  const float* x    = (const float*)d_in[0];  // [32,1024,16]
  const float* W    = (const float*)d_in[1];  // [1,1024,64,32,16]
  const float* bias = (const float*)d_in[2];  // [1,1,64,32]
  float* out = (float*)d_out;                 // [32,64,32]

  char* ws = (char*)d_ws;
  // Workspace layout (140.25 MiB — unchanged proven footprint; bij slot unused):
  //   [0,128M)      uhat  bf16 u_hat[b][i][k][o][j]  (permuted)
  //   [136,140M)    part  bf16 partials [b,32,·] (permuted rows)
  //   [140M,+256K)  vbuf  fp32 v[b,od]  (v0, then v0+v1 in place)
  uint16_t* uhat1 = (uint16_t*)ws;
  uint4*    uhat4 = (uint4*)ws;
  uint4* part = (uint4*)(ws + 134217728ull + 8388608ull);
  uint16_t* part16 = (uint16_t*)part;
  float* vbuf = (float*)(ws + 134217728ull + 8388608ull + 4194304ull);

  k_einsum<<<dim3(I_ * 4), dim3(256), 0, stream>>>(x, W, uhat1);
  // iter 0: uniform c = 1/64; v = v0
  k_sum0  <<<dim3(1024), dim3(256), 0, stream>>>(uhat4, part);
  k_squash<<<dim3(512),  dim3(256), 0, stream>>>(part16, bias, vbuf, 1.f / 64.f, 0, 0);
  // iter 1: c1 = softmax(u.v0); then v = v0+v1 (bij-free algebra)
  k_route <<<dim3(1024), dim3(256), 0, stream>>>(uhat4, vbuf, part);
  k_squash<<<dim3(512),  dim3(256), 0, stream>>>(part16, bias, vbuf, 1.f, 0, 1);
  // iter 2 (last): c2 = softmax(u.(v0+v1)); + bias -> output
  k_route <<<dim3(1024), dim3(256), 0, stream>>>(uhat4, vbuf, part);
  k_squash<<<dim3(512),  dim3(256), 0, stream>>>(part16, bias, out, 1.f, 1, 0);
}